// Round 1
// baseline (224.600 us; speedup 1.0000x reference)
//
#include <hip/hip_runtime.h>

// PatchMatch stereo — MI355X (gfx950)
// B=1, C=32, H=128, W=256, S=12, FILTER=3, TEMP=7, ITERATIONS=2
// 4 rounds (h,v,h,v), each a kernel launch; noise ping-pongs noise->ws0->d_out->ws0,
// final round writes disp into d_out (full overwrite).

namespace {
constexpr int C = 32;
constexpr int H = 128;
constexpr int W = 256;
constexpr int S = 12;
constexpr int HW = H * W;
constexpr int PITCH = W + 2;          // front+back zero pad for bilinear edge reads
constexpr float TEMP_OVER_C = 7.0f / 32.0f;
constexpr float INTERVAL = 1.0f / (S + 1);
}

template <int HORIZ>
__global__ __launch_bounds__(256, 4) void pm_round(
    const float* __restrict__ left,
    const float* __restrict__ right,
    const float* __restrict__ min_disp,
    const float* __restrict__ max_disp,
    const float* __restrict__ noise_in,
    float* __restrict__ noise_out,
    float* __restrict__ disp_out,
    int write_noise, int write_disp)
{
    __shared__ float sR[C * PITCH];

    const int w = threadIdx.x;          // pixel x
    const int s = blockIdx.x;           // sample group
    const int h = blockIdx.y;           // row
    const int row = h * W;

    // ---- stage right[:, h, :] channel-major into LDS (shifted by +1, zero pads) ----
    #pragma unroll
    for (int c = 0; c < C; ++c)
        sR[c * PITCH + w + 1] = right[c * HW + row + w];
    if (w < C) {
        sR[w * PITCH + 0] = 0.0f;
        sR[w * PITCH + W + 1] = 0.0f;
    }

    // ---- left pixel column into registers ----
    float la[C];
    #pragma unroll
    for (int c = 0; c < C; ++c)
        la[c] = left[c * HW + row + w];

    __syncthreads();

    const float mind = fmaxf(min_disp[row + w], 0.0f);
    const float maxd = fmaxf(max_disp[row + w], 0.0f);
    const float search = maxd - mind;
    const float sc = search * INTERVAL;                 // noise scale
    const float imin = fmaf(sc, (float)(s + 1), mind);  // interval_min[s]

    float cost[3], dsamp[3], nsamp[3];

    #pragma unroll
    for (int c = 0; c < 3; ++c) {
        // propagated noise tap
        float np;
        if (HORIZ) {
            int x = w + c - 1;
            np = (x >= 0 && x < W) ? noise_in[s * HW + row + x] : 0.0f;
        } else {
            int y = h + c - 1;
            np = (y >= 0 && y < H) ? noise_in[s * HW + y * W + w] : 0.0f;
        }
        nsamp[c] = np;
        const float disp = fmaf(np, sc, imin);
        dsamp[c] = disp;

        // bilinear sample position in right image
        const float xs = (float)w - disp;
        const float x0f = floorf(xs);
        const float frac = xs - x0f;
        const int x0 = (int)x0f;
        const float v0 = (x0 >= 0 && x0 < W) ? 1.0f : 0.0f;
        const float v1 = (x0 >= -1 && x0 < W - 1) ? 1.0f : 0.0f;
        int base = x0 < -1 ? -1 : (x0 > W - 1 ? W - 1 : x0);

        const float* p = &sR[base + 1];
        float d0 = 0.0f, d1 = 0.0f;
        #pragma unroll
        for (int k = 0; k < C; ++k) {
            const float g0 = p[0];
            const float g1 = p[1];      // adjacent -> ds_read2_b32
            d0 = fmaf(la[k], g0, d0);
            d1 = fmaf(la[k], g1, d1);
            p += PITCH;
        }
        const float w0 = (1.0f - frac) * v0;
        const float w1 = frac * v1;
        cost[c] = (w0 * d0 + w1 * d1) * TEMP_OVER_C;
    }

    // softmax over the 3 filter taps
    const float m = fmaxf(cost[0], fmaxf(cost[1], cost[2]));
    const float e0 = __expf(cost[0] - m);
    const float e1 = __expf(cost[1] - m);
    const float e2 = __expf(cost[2] - m);
    const float inv = 1.0f / (e0 + e1 + e2);
    const float ds = (e0 * dsamp[0] + e1 * dsamp[1] + e2 * dsamp[2]) * inv;
    const float dn = (e0 * nsamp[0] + e1 * nsamp[1] + e2 * nsamp[2]) * inv;

    const int o = s * HW + row + w;
    if (write_noise) noise_out[o] = dn;
    if (write_disp)  disp_out[o]  = ds;
}

extern "C" void kernel_launch(void* const* d_in, const int* in_sizes, int n_in,
                              void* d_out, int out_size, void* d_ws, size_t ws_size,
                              hipStream_t stream) {
    const float* left   = (const float*)d_in[0];
    const float* right  = (const float*)d_in[1];
    const float* mind   = (const float*)d_in[2];
    const float* maxd   = (const float*)d_in[3];
    const float* noise  = (const float*)d_in[4];
    float* out = (float*)d_out;
    float* ws0 = (float*)d_ws;          // S*H*W floats = 1.5 MB

    dim3 grid(S, H);
    dim3 block(256);

    // r0: horizontal, noise -> ws0
    pm_round<1><<<grid, block, 0, stream>>>(left, right, mind, maxd, noise, ws0, out, 1, 0);
    // r1: vertical,   ws0 -> d_out (as noise scratch)
    pm_round<0><<<grid, block, 0, stream>>>(left, right, mind, maxd, ws0, out, out, 1, 0);
    // r2: horizontal, d_out -> ws0
    pm_round<1><<<grid, block, 0, stream>>>(left, right, mind, maxd, out, ws0, out, 1, 0);
    // r3: vertical,   ws0 -> (no noise write), disp -> d_out (full overwrite)
    pm_round<0><<<grid, block, 0, stream>>>(left, right, mind, maxd, ws0, ws0, out, 0, 1);
}